// Round 17
// baseline (187.161 us; speedup 1.0000x reference)
//
#include <hip/hip_runtime.h>

typedef _Float16 f16;
typedef _Float16 f16x4 __attribute__((ext_vector_type(4)));
typedef _Float16 f16x8 __attribute__((ext_vector_type(8)));
typedef __fp16 h2 __attribute__((ext_vector_type(2)));
typedef float f32x4 __attribute__((ext_vector_type(4)));
typedef float f32x16 __attribute__((ext_vector_type(16)));

#define MFMA16(a, b, c) __builtin_amdgcn_mfma_f32_16x16x32_f16(a, b, c, 0, 0, 0)
#define MFMA32(a, b, c) __builtin_amdgcn_mfma_f32_32x32x16_f16(a, b, c, 0, 0, 0)

#if defined(__has_builtin)
#if __has_builtin(__builtin_amdgcn_fdot2)
#define HAS_FDOT2 1
#endif
#endif

typedef const __attribute__((address_space(1))) void gvoid;
typedef __attribute__((address_space(3))) void lvoid;
#define GLDS16(g, l) __builtin_amdgcn_global_load_lds((gvoid*)(g), (lvoid*)(l), 16, 0, 0)

// ---------------- kernel 0: convert weights to fp16 ----------------
__global__ __launch_bounds__(256) void wcvt_k(
    const float* __restrict__ tw, const float* __restrict__ pw,
    const float* __restrict__ gw, const float* __restrict__ ww,
    f16* __restrict__ Wall, f16* __restrict__ Wepi) {
  int i = blockIdx.x * 256 + threadIdx.x;
  if (i < 384 * 256) {
    int c = i >> 8, cp = i & 255;
    float v = (c < 128) ? tw[c * 256 + cp]
            : (c < 256) ? pw[(c - 128) * 256 + cp]
                        : gw[(c - 256) * 256 + cp];
    Wall[i] = (f16)v;
  }
  int j = i - 384 * 256;
  if (j >= 0 && j < 256 * 128) Wepi[j] = (f16)ww[j];
}

// ---------------- kernel 1: projection GEMM, reads x natively ----------------
// K and V written in SLOT-ORDERED tile layout (R13, verified).
__global__ __launch_bounds__(256) void proj_k(
    const float* __restrict__ x, const f16* __restrict__ Wall,
    const float* __restrict__ tb, const float* __restrict__ pb,
    const float* __restrict__ gb, f16* __restrict__ Q, f16* __restrict__ K,
    f16* __restrict__ Vt) {
  __shared__ f16 xs[64 * 264];
  __shared__ f16 vs[128 * 65];
  int b = blockIdx.x >> 6, nt = blockIdx.x & 63;
  int nbase = nt * 64;
  int tid = threadIdx.x;

  int nq = tid & 15, kq0 = tid >> 4;
#pragma unroll
  for (int p = 0; p < 4; ++p) {
    int kq = kq0 + 16 * p;
    float4 ld[4];
#pragma unroll
    for (int j = 0; j < 4; ++j)
      ld[j] = *(const float4*)(x + ((size_t)b * 256 + 4 * kq + j) * 4096 + nbase + 4 * nq);
#pragma unroll
    for (int e = 0; e < 4; ++e) {
      f16x4 wv = {(f16)((&ld[0].x)[e]), (f16)((&ld[1].x)[e]), (f16)((&ld[2].x)[e]),
                  (f16)((&ld[3].x)[e])};
      *(f16x4*)(&xs[(4 * nq + e) * 264 + 4 * kq]) = wv;
    }
  }
  __syncthreads();

  int w = tid >> 6, lane = tid & 63;
  int lr = lane & 15, lhi = lane >> 4;
  f16x8 a[8];
#pragma unroll
  for (int ks = 0; ks < 8; ++ks)
    a[ks] = *(const f16x8*)(&xs[(w * 16 + lr) * 264 + ks * 32 + lhi * 8]);
  f32x4 acc[24];
#pragma unroll
  for (int ct = 0; ct < 24; ++ct) {
    acc[ct] = {0.f, 0.f, 0.f, 0.f};
    const f16x8* wr = (const f16x8*)(Wall + (size_t)(ct * 16 + lr) * 256);
#pragma unroll
    for (int ks = 0; ks < 8; ++ks) acc[ct] = MFMA16(a[ks], wr[ks * 4 + lhi], acc[ct]);
  }
  int nloc = w * 16 + lhi * 4;
#pragma unroll
  for (int ct = 0; ct < 24; ++ct) {
    int c = ct * 16 + lr;
    float bias = (c < 128) ? tb[c] : (c < 256) ? pb[c - 128] : gb[c - 256];
#pragma unroll
    for (int r = 0; r < 4; ++r) {
      float v = acc[ct][r] + bias;
      int n = nbase + nloc + r;
      if (c < 128) {
        Q[((size_t)b * 4096 + n) * 128 + c] = (f16)v;
      } else if (c < 256) {
        int d = c - 128;
        int slot = ((d >> 4) << 6) + ((n & 31) << 1) + ((d >> 3) & 1);
        K[(size_t)b * 524288 + (size_t)(n >> 5) * 4096 + slot * 8 + (d & 7)] = (f16)v;
      } else {
        vs[(c - 256) * 65 + nloc + r] = (f16)v;
      }
    }
  }
  __syncthreads();
  f16* vo = Vt + (size_t)b * 524288;
  for (int rep = 0; rep < 32; ++rep) {
    int idx = rep * 256 + tid;
    int c = idx >> 6, j = idx & 63;  // c = channel d, j = local kv
    int n = nbase + j;
    int nl = j & 31;
    int p = (nl & 3) | ((nl & 4) << 1) | ((nl & 8) >> 1) | (nl & 16);
    int g = p >> 3, e = p & 7;
    int slot = ((c >> 5) << 7) + ((g >> 1) << 6) + ((c & 31) << 1) + (g & 1);
    vo[(size_t)(n >> 5) * 4096 + slot * 8 + e] = vs[c * 65 + j];
  }
}

// ---------------- kernel 2: flash attention, 64 q/wave (2 q-groups) ----------
// R16 diagnosis: LDS pipe oversubscribed 1.5x (one b128 read per MFMA; 4 SIMDs
// x 12cyc read vs 32cyc MFMA). Fix: each wave owns 64 q rows; every K/V
// fragment read feeds TWO MFMAs (one per q-group) -> LDS demand 0.75x, reads
// and conflicts halve. Regs ~244 peak (yacc 128 + bq 64 + s 32 + misc) fits
// (256,2). No phase-shift (cost 32 regs for +6us). Loop = R13 2-buffer sync.
__global__ __launch_bounds__(256, 2) void attn_k(const f16* __restrict__ Q,
                                                 const f16* __restrict__ K,
                                                 const f16* __restrict__ Vt,
                                                 f16* __restrict__ Yp,
                                                 float2* __restrict__ ml) {
  __shared__ f16 Ks[2][32 * 128];  // 8KB per buf, slot-ordered
  __shared__ f16 Vs[2][128 * 32];  // 8KB per buf, slot-ordered
  const float L = 1.44269504f;
  int swzid = ((blockIdx.x & 7) << 6) | ((int)blockIdx.x >> 3);
  int b = swzid >> 6, rem = swzid & 63;
  int qt = rem >> 2, s = rem & 3;
  int qbase = qt * 256;
  int tile0 = s * 32;
  int tid = threadIdx.x;
  int w = tid >> 6, lane = tid & 63;
  int col = lane & 31, hi = lane >> 5;

  const f16* Qr = Q + ((size_t)b * 4096 + qbase + w * 64 + col) * 128;
  f16x8 bq0[8], bq1[8];
#pragma unroll
  for (int ks = 0; ks < 8; ++ks) {
    bq0[ks] = *(const f16x8*)(Qr + ks * 16 + hi * 8);
    bq1[ks] = *(const f16x8*)(Qr + 32 * 128 + ks * 16 + hi * 8);
  }

  f32x16 y0[4], y1[4];
#pragma unroll
  for (int dt = 0; dt < 4; ++dt)
#pragma unroll
    for (int r = 0; r < 16; ++r) {
      y0[dt][r] = 0.f;
      y1[dt][r] = 0.f;
    }
  float lv0 = 0.f, lv1 = 0.f;
  float m0 = -1e30f, nmL0 = 1e30f;
  float m1 = -1e30f, nmL1 = 1e30f;

  const char* KbB = (const char*)(K + (size_t)b * 524288);
  const char* VbB = (const char*)(Vt + (size_t)b * 524288);
  char* KsB = (char*)&Ks[0][0];
  char* VsB = (char*)&Vs[0][0];

  auto stage = [&](int t, int buf) {  // exactly 4 GLDS per wave
    size_t tb_ = (size_t)(tile0 + t) * 8192;
    const char* kb = KbB + tb_ + w * 2048 + lane * 16;
    const char* vb = VbB + tb_ + w * 2048 + lane * 16;
    char* kl = KsB + buf * 8192 + w * 2048;
    char* vl = VsB + buf * 8192 + w * 2048;
#pragma unroll
    for (int c = 0; c < 2; ++c) {
      GLDS16(kb + c * 1024, kl + c * 1024);
      GLDS16(vb + c * 1024, vl + c * 1024);
    }
  };

  int lanebase = col * 32 + hi * 16;

  stage(0, 0);

  for (int t = 0; t < 32; ++t) {
    int cur = t & 1;
    __syncthreads();  // compiler drains vmcnt before barrier: tile t resident
    if (t + 1 < 32) stage(t + 1, cur ^ 1);

    // ---- S^T = K . Q^T for BOTH q-groups (each ak read feeds 2 MFMAs) ----
    f32x16 s0, s1;
#pragma unroll
    for (int r = 0; r < 16; ++r) {
      s0[r] = 0.f;
      s1[r] = 0.f;
    }
    __builtin_amdgcn_s_setprio(1);
    {
      const char* kcur = KsB + cur * 8192 + lanebase;
#pragma unroll
      for (int ks = 0; ks < 8; ++ks) {
        f16x8 ak = *(const f16x8*)(kcur + ks * 1024);
        s0 = MFMA32(ak, bq0[ks], s0);
        s1 = MFMA32(ak, bq1[ks], s1);
      }
    }
    __builtin_amdgcn_s_setprio(0);

    // ---- softmax group 0 ----
    f16x8 p0A, p0B, p1A, p1B;
    {
      float a0 = fmaxf(fmaxf(s0[0], s0[1]), s0[2]);
      float a1 = fmaxf(fmaxf(s0[3], s0[4]), s0[5]);
      float a2 = fmaxf(fmaxf(s0[6], s0[7]), s0[8]);
      float a3 = fmaxf(fmaxf(s0[9], s0[10]), s0[11]);
      float a4 = fmaxf(fmaxf(s0[12], s0[13]), s0[14]);
      float pm = fmaxf(fmaxf(fmaxf(a0, a1), fmaxf(a2, a3)), fmaxf(a4, s0[15]));
      pm = fmaxf(pm, __shfl_xor(pm, 32));
      if (pm > m0 + 8.f) {  // T13 defer-max
        float sc = __expf(m0 - pm);
        m0 = pm;
        nmL0 = -m0 * L;
        lv0 *= sc;
#pragma unroll
        for (int dt = 0; dt < 4; ++dt)
#pragma unroll
          for (int r = 0; r < 16; ++r) y0[dt][r] *= sc;
      }
#pragma unroll
      for (int r = 0; r < 16; ++r) s0[r] = exp2f(fmaf(s0[r], L, nmL0));
#pragma unroll
      for (int c = 0; c < 8; ++c) {
        p0A[c] = (f16)s0[c];
        p0B[c] = (f16)s0[8 + c];
      }
    }
    // ---- softmax group 1 ----
    {
      float a0 = fmaxf(fmaxf(s1[0], s1[1]), s1[2]);
      float a1 = fmaxf(fmaxf(s1[3], s1[4]), s1[5]);
      float a2 = fmaxf(fmaxf(s1[6], s1[7]), s1[8]);
      float a3 = fmaxf(fmaxf(s1[9], s1[10]), s1[11]);
      float a4 = fmaxf(fmaxf(s1[12], s1[13]), s1[14]);
      float pm = fmaxf(fmaxf(fmaxf(a0, a1), fmaxf(a2, a3)), fmaxf(a4, s1[15]));
      pm = fmaxf(pm, __shfl_xor(pm, 32));
      if (pm > m1 + 8.f) {
        float sc = __expf(m1 - pm);
        m1 = pm;
        nmL1 = -m1 * L;
        lv1 *= sc;
#pragma unroll
        for (int dt = 0; dt < 4; ++dt)
#pragma unroll
          for (int r = 0; r < 16; ++r) y1[dt][r] *= sc;
      }
#pragma unroll
      for (int r = 0; r < 16; ++r) s1[r] = exp2f(fmaf(s1[r], L, nmL1));
#pragma unroll
      for (int c = 0; c < 8; ++c) {
        p1A[c] = (f16)s1[c];
        p1B[c] = (f16)s1[8 + c];
      }
    }
#if defined(HAS_FDOT2)
    {
      h2 one2 = {1.0f, 1.0f};
      const h2* q0a = (const h2*)&p0A;
      const h2* q0b = (const h2*)&p0B;
      const h2* q1a = (const h2*)&p1A;
      const h2* q1b = (const h2*)&p1B;
      float t0 = 0.f, t1 = 0.f, t2 = 0.f, t3 = 0.f;
#pragma unroll
      for (int j = 0; j < 4; ++j) {
        t0 = __builtin_amdgcn_fdot2(q0a[j], one2, t0, false);
        t1 = __builtin_amdgcn_fdot2(q0b[j], one2, t1, false);
        t2 = __builtin_amdgcn_fdot2(q1a[j], one2, t2, false);
        t3 = __builtin_amdgcn_fdot2(q1b[j], one2, t3, false);
      }
      lv0 += t0 + t1;
      lv1 += t2 + t3;
    }
#else
    {
      float t0 = 0.f, t1 = 0.f;
#pragma unroll
      for (int c = 0; c < 8; ++c) {
        t0 += (float)p0A[c] + (float)p0B[c];
        t1 += (float)p1A[c] + (float)p1B[c];
      }
      lv0 += t0;
      lv1 += t1;
    }
#endif

    // ---- Y^T += V . P for BOTH groups (each av read feeds 2 MFMAs) ----
    __builtin_amdgcn_s_setprio(1);
    {
      const char* vcur = VsB + cur * 8192 + lanebase;
#pragma unroll
      for (int dt = 0; dt < 4; ++dt) {
        f16x8 av0 = *(const f16x8*)(vcur + dt * 2048);
        y0[dt] = MFMA32(av0, p0A, y0[dt]);
        y1[dt] = MFMA32(av0, p1A, y1[dt]);
        f16x8 av1 = *(const f16x8*)(vcur + dt * 2048 + 1024);
        y0[dt] = MFMA32(av1, p0B, y0[dt]);
        y1[dt] = MFMA32(av1, p1B, y1[dt]);
      }
    }
    __builtin_amdgcn_s_setprio(0);
  }

  float l0 = lv0 + __shfl_xor(lv0, 32);
  float l1 = lv1 + __shfl_xor(lv1, 32);

  int rowG = b * 4096 + qbase + w * 64 + col;
  float inv0 = 1.0f / l0, inv1 = 1.0f / l1;
  f16* yo0 = Yp + ((size_t)s * 32768 + rowG) * 128;
  f16* yo1 = yo0 + (size_t)32 * 128;
#pragma unroll
  for (int dt = 0; dt < 4; ++dt)
#pragma unroll
    for (int a = 0; a < 4; ++a) {
      f16x4 ov0 = {(f16)(y0[dt][4 * a] * inv0), (f16)(y0[dt][4 * a + 1] * inv0),
                   (f16)(y0[dt][4 * a + 2] * inv0), (f16)(y0[dt][4 * a + 3] * inv0)};
      *(f16x4*)(yo0 + dt * 32 + a * 8 + hi * 4) = ov0;
      f16x4 ov1 = {(f16)(y1[dt][4 * a] * inv1), (f16)(y1[dt][4 * a + 1] * inv1),
                   (f16)(y1[dt][4 * a + 2] * inv1), (f16)(y1[dt][4 * a + 3] * inv1)};
      *(f16x4*)(yo1 + dt * 32 + a * 8 + hi * 4) = ov1;
    }
  if (hi == 0) {
    ml[s * 32768 + rowG] = make_float2(m0, l0);
    ml[s * 32768 + rowG + 32] = make_float2(m1, l1);
  }
}

// ---------------- kernel 3: 4-way combine + epilogue GEMM + bias + residual ----
__global__ __launch_bounds__(256) void epi_k(const f16* __restrict__ Yp,
                                             const float2* __restrict__ ml,
                                             const f16* __restrict__ Wepi,
                                             const float* __restrict__ Wb,
                                             const float* __restrict__ x,
                                             float* __restrict__ out) {
  int b = blockIdx.x >> 6, nt = blockIdx.x & 63;
  int nbase = nt * 64;
  int w = threadIdx.x >> 6, lane = threadIdx.x & 63;
  int lr = lane & 15, lhi = lane >> 4;
  f16x8 by[4][4];
#pragma unroll
  for (int n4 = 0; n4 < 4; ++n4) {
    int row = b * 4096 + nbase + n4 * 16 + lr;
    float2 m0 = ml[row], m1 = ml[32768 + row], m2 = ml[65536 + row], m3 = ml[98304 + row];
    float mm = fmaxf(fmaxf(m0.x, m1.x), fmaxf(m2.x, m3.x));
    float w0 = m0.y * __expf(m0.x - mm), w1 = m1.y * __expf(m1.x - mm);
    float w2 = m2.y * __expf(m2.x - mm), w3 = m3.y * __expf(m3.x - mm);
    float inv = 1.f / (w0 + w1 + w2 + w3);
    w0 *= inv; w1 *= inv; w2 *= inv; w3 *= inv;
    size_t rb = (size_t)row * 128;
#pragma unroll
    for (int ks = 0; ks < 4; ++ks) {
      int eo = ks * 32 + lhi * 8;
      f16x8 a0 = *(const f16x8*)(Yp + rb + eo);
      f16x8 a1 = *(const f16x8*)(Yp + (size_t)32768 * 128 + rb + eo);
      f16x8 a2 = *(const f16x8*)(Yp + (size_t)65536 * 128 + rb + eo);
      f16x8 a3 = *(const f16x8*)(Yp + (size_t)98304 * 128 + rb + eo);
      f16x8 o;
#pragma unroll
      for (int e = 0; e < 8; ++e)
        o[e] = (f16)(w0 * (float)a0[e] + w1 * (float)a1[e] + w2 * (float)a2[e] +
                     w3 * (float)a3[e]);
      by[n4][ks] = o;
    }
  }
#pragma unroll
  for (int ot = 0; ot < 4; ++ot) {
    int o0 = w * 64 + ot * 16;
    const f16x8* wr = (const f16x8*)(Wepi + (size_t)(o0 + lr) * 128);
    f16x8 a[4];
#pragma unroll
    for (int ks = 0; ks < 4; ++ks) a[ks] = wr[ks * 4 + lhi];
#pragma unroll
    for (int n4 = 0; n4 < 4; ++n4) {
      f32x4 acc = {0.f, 0.f, 0.f, 0.f};
#pragma unroll
      for (int ks = 0; ks < 4; ++ks) acc = MFMA16(a[ks], by[n4][ks], acc);
#pragma unroll
      for (int r = 0; r < 4; ++r) {
        int o = o0 + lhi * 4 + r;
        int n = nbase + n4 * 16 + lr;
        size_t idx = ((size_t)b * 256 + o) * 4096 + n;
        out[idx] = x[idx] + Wb[o] + acc[r];
      }
    }
  }
}

extern "C" void kernel_launch(void* const* d_in, const int* in_sizes, int n_in,
                              void* d_out, int out_size, void* d_ws, size_t ws_size,
                              hipStream_t stream) {
  const float* x       = (const float*)d_in[0];
  const float* g_w     = (const float*)d_in[1];
  const float* g_b     = (const float*)d_in[2];
  const float* theta_w = (const float*)d_in[3];
  const float* theta_b = (const float*)d_in[4];
  const float* phi_w   = (const float*)d_in[5];
  const float* phi_b   = (const float*)d_in[6];
  const float* W_w     = (const float*)d_in[7];
  const float* W_b     = (const float*)d_in[8];
  float* out = (float*)d_out;

  f16* Q    = (f16*)d_ws;                       // [8,4096,128] 8MB
  f16* Kk   = Q + (size_t)8 * 4096 * 128;       // 8MB (slot-ordered tiles)
  f16* Vt   = Kk + (size_t)8 * 4096 * 128;      // 8MB (slot-ordered tiles)
  f16* Wall = Vt + (size_t)8 * 4096 * 128;      // [384,256]
  f16* Wepi = Wall + 384 * 256;                 // [256,128]
  float2* ml = (float2*)(Wepi + 256 * 128);     // [4][32768] 1MB
  f16* Yp   = (f16*)(ml + 4 * 32768);           // [4][32768][128] 32MB (~57.3MB total)

  wcvt_k<<<512, 256, 0, stream>>>(theta_w, phi_w, g_w, W_w, Wall, Wepi);
  proj_k<<<512, 256, 0, stream>>>(x, Wall, theta_b, phi_b, g_b, Q, Kk, Vt);
  attn_k<<<512, 256, 0, stream>>>(Q, Kk, Vt, Yp, ml);
  epi_k<<<512, 256, 0, stream>>>(Yp, ml, Wepi, W_b, x, out);
}